// Round 4
// baseline (130.298 us; speedup 1.0000x reference)
//
#include <hip/hip_runtime.h>
#include <math.h>

#define NN 8192
#define DIM 128
#define TILE 128
#define NT (NN / TILE)               // 64 tiles per dim
#define NTILES (NT * (NT + 1) / 2)   // 2080 upper-triangular tiles
#define TPB 4                        // tiles per block
#define NSEG (NTILES / TPB)          // 520 blocks (exact)

typedef short bf16x8 __attribute__((ext_vector_type(8)));
typedef float f32x4 __attribute__((ext_vector_type(4)));

__device__ inline void gload_lds16(const void* g, void* l) {
    __builtin_amdgcn_global_load_lds((const __attribute__((address_space(1))) void*)g,
                                     (__attribute__((address_space(3))) void*)l, 16, 0, 0);
}

__device__ inline unsigned short f2bf(float x) {
    unsigned u = __float_as_uint(x);
    unsigned r = u + 0x7FFFu + ((u >> 16) & 1u);  // round-to-nearest-even
    return (unsigned short)(r >> 16);
}
__device__ inline float bf2f(unsigned short h) {
    return __uint_as_float(((unsigned)h) << 16);
}

// ---------------------------------------------------------------------------
// Kernel 0: fp32 -> (hi, lo) bf16 split.  buf[0][N][DIM]=hi, buf[1][N][DIM]=lo
// ---------------------------------------------------------------------------
__global__ void convert_kernel(const float* __restrict__ m, unsigned short* __restrict__ buf) {
    int i = (blockIdx.x * 256 + threadIdx.x) * 4;
    float4 v = *reinterpret_cast<const float4*>(m + i);
    float f[4] = {v.x, v.y, v.z, v.w};
    ushort4 hv, lv;
    unsigned short* hp = (unsigned short*)&hv;
    unsigned short* lp = (unsigned short*)&lv;
#pragma unroll
    for (int q = 0; q < 4; ++q) {
        unsigned short h = f2bf(f[q]);
        hp[q] = h;
        lp[q] = f2bf(f[q] - bf2f(h));
    }
    *reinterpret_cast<ushort4*>(buf + i) = hv;
    *reinterpret_cast<ushort4*>(buf + NN * DIM + i) = lv;
}

// ---------------------------------------------------------------------------
// Kernel 1: per-row squared norms from ORIGINAL fp32 (exact)
// ---------------------------------------------------------------------------
__global__ void sq_kernel(const float* __restrict__ mapping, float* __restrict__ sq) {
    int i = blockIdx.x * blockDim.x + threadIdx.x;
    if (i < NN) {
        const float4* row = reinterpret_cast<const float4*>(mapping + (size_t)i * DIM);
        float s = 0.f;
#pragma unroll
        for (int q = 0; q < DIM / 4; ++q) {
            float4 v = row[q];
            s += v.x * v.x + v.y * v.y + v.z * v.z + v.w * v.w;
        }
        sq[i] = s;
    }
}

// ---------------------------------------------------------------------------
// Kernel 2: persistent 4-tile blocks, 512 threads (8 waves), 128x128 tiles.
// Wave w owns output rows [w*16, w*16+16) of the tile, all 128 cols.
//  - A fragments: REGISTERS (reload only when tile row-panel changes)
//  - B tile: 64 KiB LDS (64 chunks x 1 KiB, MFMA fragment order), staged via
//    global_load_lds; consumed via ds_read -> lgkmcnt channel only.
//  - D + sq: issued AFTER all staging vmem of the tile -> stays in flight
//    through the whole MFMA phase (counted vmcnt, raw barriers, no drains).
// Per-tile schedule:
//   [lgkmcnt(0); s_barrier]  (LDS overwrite guard; D(t-1) stays in flight)
//   [A reload if row changed] [stage B(t)] [epilogue(t-1)] [issue D(t)+sq(t)]
//   [vmcnt(17); s_barrier]   (staging done; exactly D+sq left outstanding)
//   [MFMA(t) via ds_read]
// ---------------------------------------------------------------------------
__global__ __launch_bounds__(512, 2) void dist_kernel(const unsigned short* __restrict__ buf,
                                                      const float* __restrict__ D,
                                                      const float* __restrict__ sq,
                                                      float* __restrict__ partials) {
    __shared__ unsigned short lds[32768];  // 64 KiB

    const int t = threadIdx.x;
    const int lane = t & 63;
    const int w = t >> 6;  // 0..7
    const int seg = blockIdx.x;

    const int frag_off = (lane & 15) * DIM + (lane >> 4) * 8;  // MFMA frag order
    const int colg = (lane >> 4) * 4;                          // C/D col group base

    bf16x8 afrag[4][2];  // [kq][h]
    f32x4 acc[8];
    float4 dreg[8];
    float4 sqb[8];
    float sqa = 0.f;
    float tsum = 0.f;

    int prev_bi = -1;
    int p_arow = 0, p_rowB0 = 0;
    float p_wt = 1.f;

    for (int tt = 0; tt < TPB; ++tt) {
        const int idx = seg * TPB + tt;
        int bi = 0, rem = idx, rl = NT;
        while (rem >= rl) { rem -= rl; ++bi; --rl; }
        const int bj = bi + rem;
        const int rowA0 = bi * TILE, rowB0 = bj * TILE;
        const int a_row = rowA0 + w * 16 + (lane & 15);

        if (tt > 0) {
            // all waves done ds_reading previous B tile; D(t-1) stays in flight
            asm volatile("s_waitcnt lgkmcnt(0)" ::: "memory");
            __builtin_amdgcn_s_barrier();
        }

        // ---- A fragments (registers), reload on row-panel change ----
        if (bi != prev_bi) {
            const unsigned short* ab = buf + (size_t)(rowA0 + w * 16) * DIM + frag_off;
#pragma unroll
            for (int kq = 0; kq < 4; ++kq)
#pragma unroll
                for (int h = 0; h < 2; ++h)
                    afrag[kq][h] = *(const bf16x8*)(ab + (size_t)h * (NN * DIM) + kq * 32);
        }
        prev_bi = bi;

        // ---- stage B tile: wave w stages chunks c = w*8 + kq*2 + h ----
        {
            const unsigned short* bb = buf + (size_t)(rowB0 + w * 16) * DIM + frag_off;
#pragma unroll
            for (int kq = 0; kq < 4; ++kq)
#pragma unroll
                for (int h = 0; h < 2; ++h) {
                    const int c = w * 8 + kq * 2 + h;
                    gload_lds16(bb + (size_t)h * (NN * DIM) + kq * 32, (void*)&lds[c * 512]);
                }
        }

        // ---- epilogue of previous tile (overlaps staging DMA + D stream) ----
        if (tt > 0) {
            float lsum = 0.f;
#pragma unroll
            for (int j = 0; j < 8; ++j) {
                const int bc0 = p_rowB0 + j * 16 + colg;
                const float Dv[4] = {dreg[j].x, dreg[j].y, dreg[j].z, dreg[j].w};
                const float sb[4] = {sqb[j].x, sqb[j].y, sqb[j].z, sqb[j].w};
#pragma unroll
                for (int r = 0; r < 4; ++r) {
                    float d2 = sqa + sb[r] - 2.f * acc[j][r];
                    float d = d2 > 0.f ? sqrtf(d2) : 0.f;
                    if (p_arow != bc0 + r) lsum += __fdividef(fabsf(d - Dv[r]), Dv[r]);
                }
            }
            tsum += p_wt * lsum;
        }

        // ---- issue D + sq for THIS tile (newest vmem -> stays in flight) ----
#pragma unroll
        for (int j = 0; j < 8; ++j)
            dreg[j] = *reinterpret_cast<const float4*>(
                D + (size_t)a_row * NN + (rowB0 + j * 16 + colg));
#pragma unroll
        for (int j = 0; j < 8; ++j)
            sqb[j] = *reinterpret_cast<const float4*>(sq + rowB0 + j * 16 + colg);
        sqa = sq[a_row];

        p_arow = a_row; p_rowB0 = rowB0; p_wt = (bi != bj) ? 2.f : 1.f;

        // staging complete (17 = D(8)+sqb(8)+sqa(1) newer ops left in flight)
        asm volatile("s_waitcnt vmcnt(17)" ::: "memory");
        __builtin_amdgcn_s_barrier();
        __builtin_amdgcn_sched_barrier(0);

        // ---- MFMA phase: ds_read (lgkmcnt) only; D streams underneath ----
#pragma unroll
        for (int j = 0; j < 8; ++j) acc[j] = (f32x4)0.f;
#pragma unroll
        for (int kq = 0; kq < 4; ++kq) {
#pragma unroll
            for (int j = 0; j < 8; ++j) {
                bf16x8 bh = *(const bf16x8*)&lds[(j * 8 + kq * 2 + 0) * 512 + lane * 8];
                bf16x8 bl = *(const bf16x8*)&lds[(j * 8 + kq * 2 + 1) * 512 + lane * 8];
                acc[j] = __builtin_amdgcn_mfma_f32_16x16x32_bf16(bh, afrag[kq][0], acc[j], 0, 0, 0);
                acc[j] = __builtin_amdgcn_mfma_f32_16x16x32_bf16(bl, afrag[kq][0], acc[j], 0, 0, 0);
                acc[j] = __builtin_amdgcn_mfma_f32_16x16x32_bf16(bh, afrag[kq][1], acc[j], 0, 0, 0);
            }
        }
    }

    // ---- final epilogue (tile TPB-1) ----
    {
        float lsum = 0.f;
#pragma unroll
        for (int j = 0; j < 8; ++j) {
            const int bc0 = p_rowB0 + j * 16 + colg;
            const float Dv[4] = {dreg[j].x, dreg[j].y, dreg[j].z, dreg[j].w};
            const float sb[4] = {sqb[j].x, sqb[j].y, sqb[j].z, sqb[j].w};
#pragma unroll
            for (int r = 0; r < 4; ++r) {
                float d2 = sqa + sb[r] - 2.f * acc[j][r];
                float d = d2 > 0.f ? sqrtf(d2) : 0.f;
                if (p_arow != bc0 + r) lsum += __fdividef(fabsf(d - Dv[r]), Dv[r]);
            }
        }
        tsum += p_wt * lsum;
    }

    // ---- deterministic block reduction (8 waves) ----
    for (int off = 32; off > 0; off >>= 1) tsum += __shfl_down(tsum, off, 64);
    __syncthreads();  // full drain OK here; also guards LDS reuse below
    float* wsum = (float*)lds;
    if (lane == 0) wsum[w] = tsum;
    __syncthreads();
    if (t == 0) {
        float s = 0.f;
#pragma unroll
        for (int k = 0; k < 8; ++k) s += wsum[k];
        partials[seg] = s;
    }
}

// ---------------------------------------------------------------------------
// Kernel 3: deterministic final reduction
// ---------------------------------------------------------------------------
__global__ void reduce_kernel(const float* __restrict__ partials, float* __restrict__ out) {
    __shared__ double sm[256];
    const int t = threadIdx.x;
    double s = 0.0;
    for (int i = t; i < NSEG; i += 256) s += (double)partials[i];
    sm[t] = s;
    __syncthreads();
    for (int off = 128; off > 0; off >>= 1) {
        if (t < off) sm[t] += sm[t + off];
        __syncthreads();
    }
    if (t == 0) out[0] = (float)(sm[0] / ((double)NN * (double)NN - (double)NN));
}

// ---------------------------------------------------------------------------
extern "C" void kernel_launch(void* const* d_in, const int* in_sizes, int n_in,
                              void* d_out, int out_size, void* d_ws, size_t ws_size,
                              hipStream_t stream) {
    const float* mapping = (const float*)d_in[0];
    const float* D       = (const float*)d_in[1];
    float* out = (float*)d_out;

    unsigned short* buf = (unsigned short*)d_ws;            // 2 * NN * DIM bf16 = 4 MiB
    float* sq           = (float*)(buf + 2 * NN * DIM);     // NN floats
    float* partials     = sq + NN;                          // NSEG floats

    convert_kernel<<<(NN * DIM) / 1024, 256, 0, stream>>>(mapping, buf);
    sq_kernel<<<NN / 256, 256, 0, stream>>>(mapping, sq);
    dist_kernel<<<NSEG, 512, 0, stream>>>(buf, D, sq, partials);
    reduce_kernel<<<1, 256, 0, stream>>>(partials, out);
}

// Round 5
// 112.245 us; speedup vs baseline: 1.1608x; 1.1608x over previous
//
#include <hip/hip_runtime.h>
#include <math.h>

#define NN 8192
#define DIM 128
#define NT32 (NN / 32)                     // 256 strips
#define TOTTILES (NT32 * (NT32 + 1) / 2)   // 32896 upper-tri 32x32 tiles
#define NBLOCKS 512
#define NWAVES (NBLOCKS * 4)               // 2048 waves
#define BASE_T (TOTTILES / NWAVES)         // 16
#define EXTRA (TOTTILES - BASE_T * NWAVES) // 128

typedef short bf16x8 __attribute__((ext_vector_type(8)));
typedef float f32x4 __attribute__((ext_vector_type(4)));

__device__ inline unsigned short f2bf(float x) {
    unsigned u = __float_as_uint(x);
    unsigned r = u + 0x7FFFu + ((u >> 16) & 1u);  // round-to-nearest-even
    return (unsigned short)(r >> 16);
}
__device__ inline float bf2f(unsigned short h) {
    return __uint_as_float(((unsigned)h) << 16);
}

// ---------------------------------------------------------------------------
// Kernel 0: fp32 -> (hi, lo) bf16 split.  buf[0][N][DIM]=hi, buf[1][N][DIM]=lo
// ---------------------------------------------------------------------------
__global__ void convert_kernel(const float* __restrict__ m, unsigned short* __restrict__ buf) {
    int i = (blockIdx.x * 256 + threadIdx.x) * 4;
    float4 v = *reinterpret_cast<const float4*>(m + i);
    float f[4] = {v.x, v.y, v.z, v.w};
    ushort4 hv, lv;
    unsigned short* hp = (unsigned short*)&hv;
    unsigned short* lp = (unsigned short*)&lv;
#pragma unroll
    for (int q = 0; q < 4; ++q) {
        unsigned short h = f2bf(f[q]);
        hp[q] = h;
        lp[q] = f2bf(f[q] - bf2f(h));
    }
    *reinterpret_cast<ushort4*>(buf + i) = hv;
    *reinterpret_cast<ushort4*>(buf + NN * DIM + i) = lv;
}

// ---------------------------------------------------------------------------
// Kernel 1: per-row squared norms from ORIGINAL fp32 (exact)
// ---------------------------------------------------------------------------
__global__ void sq_kernel(const float* __restrict__ mapping, float* __restrict__ sq) {
    int i = blockIdx.x * blockDim.x + threadIdx.x;
    if (i < NN) {
        const float4* row = reinterpret_cast<const float4*>(mapping + (size_t)i * DIM);
        float s = 0.f;
#pragma unroll
        for (int q = 0; q < DIM / 4; ++q) {
            float4 v = row[q];
            s += v.x * v.x + v.y * v.y + v.z * v.z + v.w * v.w;
        }
        sq[i] = s;
    }
}

// ---------------------------------------------------------------------------
// Kernel 2: FREE-RUNNING WAVES, no LDS staging, no barriers.
// Each wave owns ~16 contiguous 32x32 tiles (strip-major, upper triangle).
//  - A-strip fragments persist in registers across a strip (64 VGPR).
//  - B fragments loaded per k-step straight from L2/L3-resident buf.
//  - D (the only HBM stream) issued FIRST each tile; per-wave counted vmcnt
//    waits only (compiler), no collective drains anywhere.
// Swapped MFMA operands (mfma(b,a)): acc[it][jt][r] = G[a][b0+r],
//   a = si*32+it*16+(lane&15),  b0 = tj*32+jt*16+(lane>>4)*4.
// ---------------------------------------------------------------------------
__global__ __launch_bounds__(256, 2) void dist_kernel(const unsigned short* __restrict__ buf,
                                                      const float* __restrict__ D,
                                                      const float* __restrict__ sq,
                                                      float* __restrict__ partials) {
    const int t = threadIdx.x;
    const int lane = t & 63;
    const int w = t >> 6;
    const int W = blockIdx.x * 4 + w;

    const int nt = BASE_T + (W < EXTRA ? 1 : 0);
    const int start = W * BASE_T + (W < EXTRA ? W : EXTRA);

    // locate (si, tj) of the first tile (strip-major triangle)
    int si = 0, base = 0;
    while (start >= base + (NT32 - si)) { base += NT32 - si; ++si; }
    int tj = si + (start - base);

    const int la = lane & 15;
    const int colg = (lane >> 4) * 4;
    const int frag_off = la * DIM + (lane >> 4) * 8;

    bf16x8 afrag[2][4][2];  // [it][kq][h]
    float sqa[2];
    float tsum = 0.f;
    int cur_si = -1;

    for (int tt = 0; tt < nt; ++tt) {
        const int bc = tj * 32;

        // ---- D + sqb: issue first (only HBM stream; stays in flight) ----
        float4 dreg[2][2];
        float4 sqb[2];
#pragma unroll
        for (int it = 0; it < 2; ++it)
#pragma unroll
            for (int jt = 0; jt < 2; ++jt)
                dreg[it][jt] = *reinterpret_cast<const float4*>(
                    D + (size_t)(si * 32 + it * 16 + la) * NN + (bc + jt * 16 + colg));
#pragma unroll
        for (int jt = 0; jt < 2; ++jt)
            sqb[jt] = *reinterpret_cast<const float4*>(sq + bc + jt * 16 + colg);

        // ---- A-strip fragments (registers), reload on strip change ----
        if (si != cur_si) {
            cur_si = si;
            const unsigned short* ab = buf + (size_t)(si * 32) * DIM + frag_off;
#pragma unroll
            for (int it = 0; it < 2; ++it) {
#pragma unroll
                for (int kq = 0; kq < 4; ++kq)
#pragma unroll
                    for (int h = 0; h < 2; ++h)
                        afrag[it][kq][h] = *(const bf16x8*)(ab + (size_t)h * (NN * DIM) +
                                                            it * 16 * DIM + kq * 32);
                sqa[it] = sq[si * 32 + it * 16 + la];
            }
        }

        // ---- B fragments from L2 + MFMA (48 per tile) ----
        f32x4 acc[2][2] = {};
        const unsigned short* bb = buf + (size_t)bc * DIM + frag_off;
#pragma unroll
        for (int kq = 0; kq < 4; ++kq) {
            bf16x8 bh[2], bl[2];
#pragma unroll
            for (int jt = 0; jt < 2; ++jt) {
                bh[jt] = *(const bf16x8*)(bb + jt * 16 * DIM + kq * 32);
                bl[jt] = *(const bf16x8*)(bb + (size_t)(NN * DIM) + jt * 16 * DIM + kq * 32);
            }
#pragma unroll
            for (int it = 0; it < 2; ++it)
#pragma unroll
                for (int jt = 0; jt < 2; ++jt) {
                    acc[it][jt] = __builtin_amdgcn_mfma_f32_16x16x32_bf16(bh[jt], afrag[it][kq][0], acc[it][jt], 0, 0, 0);
                    acc[it][jt] = __builtin_amdgcn_mfma_f32_16x16x32_bf16(bl[jt], afrag[it][kq][0], acc[it][jt], 0, 0, 0);
                    acc[it][jt] = __builtin_amdgcn_mfma_f32_16x16x32_bf16(bh[jt], afrag[it][kq][1], acc[it][jt], 0, 0, 0);
                }
        }

        // ---- epilogue ----
        float lsum = 0.f;
#pragma unroll
        for (int it = 0; it < 2; ++it) {
            const int a = si * 32 + it * 16 + la;
#pragma unroll
            for (int jt = 0; jt < 2; ++jt) {
                const int b0 = bc + jt * 16 + colg;
                const float Dv[4] = {dreg[it][jt].x, dreg[it][jt].y, dreg[it][jt].z, dreg[it][jt].w};
                const float sb[4] = {sqb[jt].x, sqb[jt].y, sqb[jt].z, sqb[jt].w};
#pragma unroll
                for (int r = 0; r < 4; ++r) {
                    float d2 = sqa[it] + sb[r] - 2.f * acc[it][jt][r];
                    float d = d2 > 0.f ? sqrtf(d2) : 0.f;
                    if (a != b0 + r) lsum += __fdividef(fabsf(d - Dv[r]), Dv[r]);
                }
            }
        }
        tsum += (tj == si) ? lsum : 2.f * lsum;

        // ---- advance tile ----
        ++tj;
        if (tj == NT32) { ++si; tj = si; }
    }

    // ---- deterministic block reduction (4 waves) ----
    for (int off = 32; off > 0; off >>= 1) tsum += __shfl_down(tsum, off, 64);
    __shared__ float wsum[4];
    if (lane == 0) wsum[w] = tsum;
    __syncthreads();
    if (t == 0) partials[blockIdx.x] = (wsum[0] + wsum[1]) + (wsum[2] + wsum[3]);
}

// ---------------------------------------------------------------------------
// Kernel 3: deterministic final reduction
// ---------------------------------------------------------------------------
__global__ void reduce_kernel(const float* __restrict__ partials, float* __restrict__ out) {
    __shared__ double sm[256];
    const int t = threadIdx.x;
    double s = 0.0;
    for (int i = t; i < NBLOCKS; i += 256) s += (double)partials[i];
    sm[t] = s;
    __syncthreads();
    for (int off = 128; off > 0; off >>= 1) {
        if (t < off) sm[t] += sm[t + off];
        __syncthreads();
    }
    if (t == 0) out[0] = (float)(sm[0] / ((double)NN * (double)NN - (double)NN));
}

// ---------------------------------------------------------------------------
extern "C" void kernel_launch(void* const* d_in, const int* in_sizes, int n_in,
                              void* d_out, int out_size, void* d_ws, size_t ws_size,
                              hipStream_t stream) {
    const float* mapping = (const float*)d_in[0];
    const float* D       = (const float*)d_in[1];
    float* out = (float*)d_out;

    unsigned short* buf = (unsigned short*)d_ws;            // 2 * NN * DIM bf16 = 4 MiB
    float* sq           = (float*)(buf + 2 * NN * DIM);     // NN floats
    float* partials     = sq + NN;                          // NBLOCKS floats

    convert_kernel<<<(NN * DIM) / 1024, 256, 0, stream>>>(mapping, buf);
    sq_kernel<<<NN / 256, 256, 0, stream>>>(mapping, sq);
    dist_kernel<<<NBLOCKS, 256, 0, stream>>>(buf, D, sq, partials);
    reduce_kernel<<<1, 256, 0, stream>>>(partials, out);
}

// Round 6
// 74.029 us; speedup vs baseline: 1.7601x; 1.5162x over previous
//
#include <hip/hip_runtime.h>
#include <math.h>

#define NN 8192
#define DIM 128
#define TS 32                            // tile side
#define NSTRIP (NN / TS)                 // 256
#define TOTTILES (NSTRIP * (NSTRIP + 1) / 2)  // 32896
#define TPW 4                            // tiles per wave
#define NWAVE (TOTTILES / TPW)           // 8224 (exact)
#define NBLOCKS (NWAVE / 4)              // 2056 blocks (4 waves each)

typedef short bf16x8 __attribute__((ext_vector_type(8)));
typedef float f32x4 __attribute__((ext_vector_type(4)));

__device__ inline unsigned short f2bf(float x) {
    unsigned u = __float_as_uint(x);
    unsigned r = u + 0x7FFFu + ((u >> 16) & 1u);  // RNE
    return (unsigned short)(r >> 16);
}

// ---------------------------------------------------------------------------
// Kernel 0: pack mapping into MFMA-fragment-order bf16 chunks.
// Chunk (g, kq) = rows g*16..+15, k = kq*32 + (lane>>4)*8 ..+7; lane l's 16B
// at chunk*1024 + l*16  ->  every fragment load is one contiguous 1KB/wave.
// ---------------------------------------------------------------------------
__global__ void pack_kernel(const float* __restrict__ m, unsigned short* __restrict__ buf2) {
    const int t = threadIdx.x, l = t & 63;
    const int W = blockIdx.x * 4 + (t >> 6);   // 0..2047 = chunk id
    const int g = W >> 2, kq = W & 3;
    const int row = g * 16 + (l & 15);
    const int k0 = kq * 32 + (l >> 4) * 8;
    const float* src = m + (size_t)row * DIM + k0;
    float4 v0 = *reinterpret_cast<const float4*>(src);
    float4 v1 = *reinterpret_cast<const float4*>(src + 4);
    float f[8] = {v0.x, v0.y, v0.z, v0.w, v1.x, v1.y, v1.z, v1.w};
    union { ushort4 u4[2]; unsigned short us[8]; } o;
#pragma unroll
    for (int q = 0; q < 8; ++q) o.us[q] = f2bf(f[q]);
    unsigned short* dst = buf2 + (size_t)W * 512 + l * 8;
    *reinterpret_cast<ushort4*>(dst) = o.u4[0];
    *reinterpret_cast<ushort4*>(dst + 4) = o.u4[1];
}

// ---------------------------------------------------------------------------
// Kernel 1: exact fp32 row norms
// ---------------------------------------------------------------------------
__global__ void sq_kernel(const float* __restrict__ mapping, float* __restrict__ sq) {
    int i = blockIdx.x * blockDim.x + threadIdx.x;
    if (i < NN) {
        const float4* row = reinterpret_cast<const float4*>(mapping + (size_t)i * DIM);
        float s = 0.f;
#pragma unroll
        for (int q = 0; q < DIM / 4; ++q) {
            float4 v = row[q];
            s += v.x * v.x + v.y * v.y + v.z * v.z + v.w * v.w;
        }
        sq[i] = s;
    }
}

// ---------------------------------------------------------------------------
// Kernel 2: free-running waves, 32x32 tiles, 4 tiles/wave, no block barriers.
//  - A strip fragments persistent in regs; B fragments = contiguous 1KB loads.
//  - 16 MFMA/tile (plain bf16 gram; split-terms dropped: scalar err ~4e-8).
//  - acc -> wave-private LDS (XOR-swizzled 128B rows) -> row-major re-read so
//    D loads are 8 rows x 128B full lines.
//  - D(t+1) issued after B(t): B-wait (in-order vmcnt) leaves D in flight
//    through MFMA+transpose; consumed next tile.
// ---------------------------------------------------------------------------
__global__ __launch_bounds__(256, 3) void dist_kernel(const unsigned short* __restrict__ buf2,
                                                      const float* __restrict__ D,
                                                      const float* __restrict__ sq,
                                                      float* __restrict__ partials) {
    __shared__ float smem[4][1024];   // 4KB per wave, wave-private
    __shared__ float wred[4];

    const int t = threadIdx.x, l = t & 63, w = t >> 6;
    const int b = blockIdx.x;
    const int nb = (b & 7) * (NBLOCKS / 8) + (b >> 3);   // XCD-chunked swizzle
    const int W = nb * 4 + w;

    // locate (si, cj) of first tile — scalar loop via readfirstlane
    int idx0 = __builtin_amdgcn_readfirstlane(W * TPW);
    int si = 0, base = 0;
    while (idx0 >= base + (NSTRIP - si)) { base += NSTRIP - si; ++si; }
    int cj = si + (idx0 - base);

    const int l15 = l & 15, l4 = l >> 4, l7 = l & 7, l3 = l >> 3;
    float* sm = smem[w];

    // ---- D(0) prefetch (row-major, 8 rows x 128B lines per instr) ----
    f32x4 dc[4];
#pragma unroll
    for (int k = 0; k < 4; ++k)
        dc[k] = *reinterpret_cast<const f32x4*>(
            D + (size_t)(si * TS + l3 + 8 * k) * NN + cj * TS + l7 * 4);

    // ---- A strip fragments ----
    bf16x8 af[2][4];
#pragma unroll
    for (int it = 0; it < 2; ++it)
#pragma unroll
        for (int kq = 0; kq < 4; ++kq)
            af[it][kq] = *(const bf16x8*)(buf2 + (size_t)((si * 2 + it) * 4 + kq) * 512 + l * 8);

    float tsum = 0.f;

#pragma unroll
    for (int tt = 0; tt < TPW; ++tt) {
        // next-tile coords (clamped on last tile)
        int nsi = si, ncj = cj + 1;
        if (ncj == NSTRIP) { nsi = si + 1; ncj = nsi; }
        if (tt == TPW - 1) { nsi = si; ncj = cj; }

        // ---- B fragments (8 x contiguous 1KB) + sq for current tile ----
        bf16x8 bf[2][4];
#pragma unroll
        for (int jt = 0; jt < 2; ++jt)
#pragma unroll
            for (int kq = 0; kq < 4; ++kq)
                bf[jt][kq] = *(const bf16x8*)(buf2 + (size_t)((cj * 2 + jt) * 4 + kq) * 512 + l * 8);
        float sqa[4];
#pragma unroll
        for (int k = 0; k < 4; ++k) sqa[k] = sq[si * TS + l3 + 8 * k];
        f32x4 sqb = *reinterpret_cast<const f32x4*>(sq + cj * TS + l7 * 4);

        // ---- issue D(t+1): newest vmem, stays in flight through MFMA ----
        f32x4 dn[4];
#pragma unroll
        for (int k = 0; k < 4; ++k)
            dn[k] = *reinterpret_cast<const f32x4*>(
                D + (size_t)(nsi * TS + l3 + 8 * k) * NN + ncj * TS + l7 * 4);
        __builtin_amdgcn_sched_barrier(0);

        // ---- 16 MFMA: acc[it][jt][r] = G[si*32+it*16+l15][cj*32+jt*16+l4*4+r] ----
        f32x4 acc[2][2] = {};
#pragma unroll
        for (int kq = 0; kq < 4; ++kq)
#pragma unroll
            for (int it = 0; it < 2; ++it)
#pragma unroll
                for (int jt = 0; jt < 2; ++jt)
                    acc[it][jt] = __builtin_amdgcn_mfma_f32_16x16x32_bf16(
                        bf[jt][kq], af[it][kq], acc[it][jt], 0, 0, 0);

        // ---- wave-private LDS transpose (XOR-swizzled 128B rows) ----
#pragma unroll
        for (int it = 0; it < 2; ++it)
#pragma unroll
            for (int jt = 0; jt < 2; ++jt) {
                const int R = it * 16 + l15;
                const int cbytes = (jt * 64 + l4 * 16) ^ ((R & 7) << 4);
                *reinterpret_cast<f32x4*>((char*)&sm[R * 32] + cbytes) = acc[it][jt];
            }
        f32x4 gv[4];
#pragma unroll
        for (int k = 0; k < 4; ++k) {
            const int R = l3 + 8 * k;
            const int cbytes = (l7 * 16) ^ ((R & 7) << 4);
            gv[k] = *reinterpret_cast<const f32x4*>((char*)&sm[R * 32] + cbytes);
        }

        // ---- epilogue: all operands row-major & in regs ----
        float lsum = 0.f;
#pragma unroll
        for (int k = 0; k < 4; ++k) {
            const int a = si * TS + l3 + 8 * k;
#pragma unroll
            for (int c = 0; c < 4; ++c) {
                const int bcol = cj * TS + l7 * 4 + c;
                float d2 = sqa[k] + sqb[c] - 2.f * gv[k][c];
                float d = d2 > 0.f ? sqrtf(d2) : 0.f;
                float Dv = dc[k][c];
                if (a != bcol) lsum += __fdividef(fabsf(d - Dv), Dv);
            }
        }
        tsum += (si == cj) ? lsum : 2.f * lsum;

        // ---- rotate pipeline, advance, A reload on strip change ----
#pragma unroll
        for (int k = 0; k < 4; ++k) dc[k] = dn[k];
        ++cj;
        if (cj == NSTRIP) {
            ++si; cj = si;
            if (tt != TPW - 1) {
#pragma unroll
                for (int it = 0; it < 2; ++it)
#pragma unroll
                    for (int kq = 0; kq < 4; ++kq)
                        af[it][kq] = *(const bf16x8*)(buf2 + (size_t)((si * 2 + it) * 4 + kq) * 512 + l * 8);
            }
        }
    }

    // ---- deterministic block reduction ----
    for (int off = 32; off > 0; off >>= 1) tsum += __shfl_down(tsum, off, 64);
    __syncthreads();
    if (l == 0) wred[w] = tsum;
    __syncthreads();
    if (t == 0) partials[b] = (wred[0] + wred[1]) + (wred[2] + wred[3]);
}

// ---------------------------------------------------------------------------
// Kernel 3: deterministic final reduction
// ---------------------------------------------------------------------------
__global__ void reduce_kernel(const float* __restrict__ partials, float* __restrict__ out) {
    __shared__ double sm[256];
    const int t = threadIdx.x;
    double s = 0.0;
    for (int i = t; i < NBLOCKS; i += 256) s += (double)partials[i];
    sm[t] = s;
    __syncthreads();
    for (int off = 128; off > 0; off >>= 1) {
        if (t < off) sm[t] += sm[t + off];
        __syncthreads();
    }
    if (t == 0) out[0] = (float)(sm[0] / ((double)NN * (double)NN - (double)NN));
}

// ---------------------------------------------------------------------------
extern "C" void kernel_launch(void* const* d_in, const int* in_sizes, int n_in,
                              void* d_out, int out_size, void* d_ws, size_t ws_size,
                              hipStream_t stream) {
    const float* mapping = (const float*)d_in[0];
    const float* D       = (const float*)d_in[1];
    float* out = (float*)d_out;

    unsigned short* buf2 = (unsigned short*)d_ws;        // NN*DIM bf16 = 2 MiB
    float* sq            = (float*)(buf2 + NN * DIM);    // NN floats
    float* partials      = sq + NN;                      // NBLOCKS floats

    pack_kernel<<<512, 256, 0, stream>>>(mapping, buf2);
    sq_kernel<<<NN / 256, 256, 0, stream>>>(mapping, sq);
    dist_kernel<<<NBLOCKS, 256, 0, stream>>>(buf2, D, sq, partials);
    reduce_kernel<<<1, 256, 0, stream>>>(partials, out);
}

// Round 7
// 73.343 us; speedup vs baseline: 1.7765x; 1.0094x over previous
//
#include <hip/hip_runtime.h>
#include <math.h>

#define NN 8192
#define DIM 128
#define TS 32                            // tile side
#define NSTRIP (NN / TS)                 // 256
#define TOTTILES (NSTRIP * (NSTRIP + 1) / 2)  // 32896
#define TPW 4                            // tiles per wave
#define NWAVE (TOTTILES / TPW)           // 8224 (exact)
#define NBLOCKS (NWAVE / 4)              // 2056 blocks = 8 * 257 (exact XCD chunks)

typedef short bf16x8 __attribute__((ext_vector_type(8)));
typedef float f32x4 __attribute__((ext_vector_type(4)));

__device__ inline unsigned short f2bf(float x) {
    unsigned u = __float_as_uint(x);
    unsigned r = u + 0x7FFFu + ((u >> 16) & 1u);  // RNE
    return (unsigned short)(r >> 16);
}

// ---------------------------------------------------------------------------
// Kernel 0: pack mapping into MFMA-fragment-order bf16 chunks (1KB/wave-load).
// ---------------------------------------------------------------------------
__global__ void pack_kernel(const float* __restrict__ m, unsigned short* __restrict__ buf2) {
    const int t = threadIdx.x, l = t & 63;
    const int W = blockIdx.x * 4 + (t >> 6);   // chunk id
    const int g = W >> 2, kq = W & 3;
    const int row = g * 16 + (l & 15);
    const int k0 = kq * 32 + (l >> 4) * 8;
    const float* src = m + (size_t)row * DIM + k0;
    float4 v0 = *reinterpret_cast<const float4*>(src);
    float4 v1 = *reinterpret_cast<const float4*>(src + 4);
    float f[8] = {v0.x, v0.y, v0.z, v0.w, v1.x, v1.y, v1.z, v1.w};
    union { ushort4 u4[2]; unsigned short us[8]; } o;
#pragma unroll
    for (int q = 0; q < 8; ++q) o.us[q] = f2bf(f[q]);
    unsigned short* dst = buf2 + (size_t)W * 512 + l * 8;
    *reinterpret_cast<ushort4*>(dst) = o.u4[0];
    *reinterpret_cast<ushort4*>(dst + 4) = o.u4[1];
}

// ---------------------------------------------------------------------------
// Kernel 1: exact fp32 row norms
// ---------------------------------------------------------------------------
__global__ void sq_kernel(const float* __restrict__ mapping, float* __restrict__ sq) {
    int i = blockIdx.x * blockDim.x + threadIdx.x;
    if (i < NN) {
        const float4* row = reinterpret_cast<const float4*>(mapping + (size_t)i * DIM);
        float s = 0.f;
#pragma unroll
        for (int q = 0; q < DIM / 4; ++q) {
            float4 v = row[q];
            s += v.x * v.x + v.y * v.y + v.z * v.z + v.w * v.w;
        }
        sq[i] = s;
    }
}

// ---------------------------------------------------------------------------
// Kernel 2: free-running waves, 32x32 tiles, 4/wave.
// KEY CHANGE vs r6: ALL 4 tiles' D issued up-front, row-group-major, so each
// DRAM row gets 512B (wave) / 2KB (block) of consecutive requests instead of
// 128B per ~700cy — attacks DRAM activation-granularity inefficiency.
// ---------------------------------------------------------------------------
__global__ __launch_bounds__(256, 3) void dist_kernel(const unsigned short* __restrict__ buf2,
                                                      const float* __restrict__ D,
                                                      const float* __restrict__ sq,
                                                      float* __restrict__ partials) {
    __shared__ float smem[4][1024];   // 4KB per wave, wave-private
    __shared__ float wred[4];

    const int t = threadIdx.x, l = t & 63, w = t >> 6;
    const int b = blockIdx.x;
    const int nb = (b & 7) * (NBLOCKS / 8) + (b >> 3);   // bijective XCD swizzle
    const int W = nb * 4 + w;

    // locate first tile; precompute all 4 (si,cj)
    int idx0 = __builtin_amdgcn_readfirstlane(W * TPW);
    int si = 0, base = 0;
    while (idx0 >= base + (NSTRIP - si)) { base += NSTRIP - si; ++si; }
    int cj = si + (idx0 - base);
    int sit[TPW], cjt[TPW];
#pragma unroll
    for (int tt = 0; tt < TPW; ++tt) {
        sit[tt] = si; cjt[tt] = cj;
        ++cj;
        if (cj == NSTRIP) { ++si; cj = si; }
    }

    const int l15 = l & 15, l4 = l >> 4, l7 = l & 7, l3 = l >> 3;
    float* sm = smem[w];

    // ---- issue ALL D for the 4 tiles, row-group-major (burst contiguity) ----
    f32x4 dall[TPW][4];
#pragma unroll
    for (int k = 0; k < 4; ++k)
#pragma unroll
        for (int tt = 0; tt < TPW; ++tt)
            dall[tt][k] = *reinterpret_cast<const f32x4*>(
                D + (size_t)(sit[tt] * TS + l3 + 8 * k) * NN + cjt[tt] * TS + l7 * 4);
    __builtin_amdgcn_sched_barrier(0);

    // ---- A strip fragments + sqa for first strip ----
    bf16x8 af[2][4];
    float sqa[4];
#pragma unroll
    for (int it = 0; it < 2; ++it)
#pragma unroll
        for (int kq = 0; kq < 4; ++kq)
            af[it][kq] = *(const bf16x8*)(buf2 + (size_t)((sit[0] * 2 + it) * 4 + kq) * 512 + l * 8);
#pragma unroll
    for (int k = 0; k < 4; ++k) sqa[k] = sq[sit[0] * TS + l3 + 8 * k];

    float tsum = 0.f;

#pragma unroll
    for (int tt = 0; tt < TPW; ++tt) {
        const int csi = sit[tt], ccj = cjt[tt];

        // A reload on strip change
        if (tt > 0 && sit[tt] != sit[tt - 1]) {
#pragma unroll
            for (int it = 0; it < 2; ++it)
#pragma unroll
                for (int kq = 0; kq < 4; ++kq)
                    af[it][kq] = *(const bf16x8*)(buf2 + (size_t)((csi * 2 + it) * 4 + kq) * 512 + l * 8);
#pragma unroll
            for (int k = 0; k < 4; ++k) sqa[k] = sq[csi * TS + l3 + 8 * k];
        }

        // B fragments (8 x contiguous 1KB from L2) + sqb
        bf16x8 bfr[2][4];
#pragma unroll
        for (int jt = 0; jt < 2; ++jt)
#pragma unroll
            for (int kq = 0; kq < 4; ++kq)
                bfr[jt][kq] = *(const bf16x8*)(buf2 + (size_t)((ccj * 2 + jt) * 4 + kq) * 512 + l * 8);
        f32x4 sqb = *reinterpret_cast<const f32x4*>(sq + ccj * TS + l7 * 4);

        // 16 MFMA: acc[it][jt][r] = G[csi*32+it*16+l15][ccj*32+jt*16+l4*4+r]
        f32x4 acc[2][2] = {};
#pragma unroll
        for (int kq = 0; kq < 4; ++kq)
#pragma unroll
            for (int it = 0; it < 2; ++it)
#pragma unroll
                for (int jt = 0; jt < 2; ++jt)
                    acc[it][jt] = __builtin_amdgcn_mfma_f32_16x16x32_bf16(
                        bfr[jt][kq], af[it][kq], acc[it][jt], 0, 0, 0);

        // wave-private LDS transpose (XOR-swizzled 128B rows)
#pragma unroll
        for (int it = 0; it < 2; ++it)
#pragma unroll
            for (int jt = 0; jt < 2; ++jt) {
                const int R = it * 16 + l15;
                const int cbytes = (jt * 64 + l4 * 16) ^ ((R & 7) << 4);
                *reinterpret_cast<f32x4*>((char*)&sm[R * 32] + cbytes) = acc[it][jt];
            }
        f32x4 gv[4];
#pragma unroll
        for (int k = 0; k < 4; ++k) {
            const int R = l3 + 8 * k;
            const int cbytes = (l7 * 16) ^ ((R & 7) << 4);
            gv[k] = *reinterpret_cast<const f32x4*>((char*)&sm[R * 32] + cbytes);
        }

        // ---- epilogue ----
        if (csi != ccj) {
            // fully off-diagonal tile: no masking, weight 2
            float lsum = 0.f;
#pragma unroll
            for (int k = 0; k < 4; ++k) {
                const float sa = sqa[k];
#pragma unroll
                for (int c = 0; c < 4; ++c) {
                    float d2 = fmaf(-2.f, gv[k][c], sa + sqb[c]);
                    float d = sqrtf(fmaxf(d2, 0.f));
                    float Dv = dall[tt][k][c];
                    lsum += __fdividef(fabsf(d - Dv), Dv);
                }
            }
            tsum += 2.f * lsum;
        } else {
            // diagonal tile: mask a<bcol, weight 2 (diag elements excluded)
            float lsum = 0.f;
#pragma unroll
            for (int k = 0; k < 4; ++k) {
                const int a = csi * TS + l3 + 8 * k;
                const float sa = sqa[k];
#pragma unroll
                for (int c = 0; c < 4; ++c) {
                    const int bcol = ccj * TS + l7 * 4 + c;
                    float d2 = fmaf(-2.f, gv[k][c], sa + sqb[c]);
                    float d = sqrtf(fmaxf(d2, 0.f));
                    float Dv = dall[tt][k][c];
                    if (a < bcol) lsum += __fdividef(fabsf(d - Dv), Dv);
                }
            }
            tsum += 2.f * lsum;
        }
    }

    // ---- deterministic block reduction ----
    for (int off = 32; off > 0; off >>= 1) tsum += __shfl_down(tsum, off, 64);
    __syncthreads();
    if (l == 0) wred[w] = tsum;
    __syncthreads();
    if (t == 0) partials[b] = (wred[0] + wred[1]) + (wred[2] + wred[3]);
}

// ---------------------------------------------------------------------------
// Kernel 3: deterministic final reduction
// ---------------------------------------------------------------------------
__global__ void reduce_kernel(const float* __restrict__ partials, float* __restrict__ out) {
    __shared__ double sm[256];
    const int t = threadIdx.x;
    double s = 0.0;
    for (int i = t; i < NBLOCKS; i += 256) s += (double)partials[i];
    sm[t] = s;
    __syncthreads();
    for (int off = 128; off > 0; off >>= 1) {
        if (t < off) sm[t] += sm[t + off];
        __syncthreads();
    }
    if (t == 0) out[0] = (float)(sm[0] / ((double)NN * (double)NN - (double)NN));
}

// ---------------------------------------------------------------------------
extern "C" void kernel_launch(void* const* d_in, const int* in_sizes, int n_in,
                              void* d_out, int out_size, void* d_ws, size_t ws_size,
                              hipStream_t stream) {
    const float* mapping = (const float*)d_in[0];
    const float* D       = (const float*)d_in[1];
    float* out = (float*)d_out;

    unsigned short* buf2 = (unsigned short*)d_ws;        // NN*DIM bf16 = 2 MiB
    float* sq            = (float*)(buf2 + NN * DIM);    // NN floats
    float* partials      = sq + NN;                      // NBLOCKS floats

    pack_kernel<<<512, 256, 0, stream>>>(mapping, buf2);
    sq_kernel<<<NN / 256, 256, 0, stream>>>(mapping, sq);
    dist_kernel<<<NBLOCKS, 256, 0, stream>>>(buf2, D, sq, partials);
    reduce_kernel<<<1, 256, 0, stream>>>(partials, out);
}